// Round 1
// baseline (947.279 us; speedup 1.0000x reference)
//
#include <hip/hip_runtime.h>

#define D 64
#define EPSV 1e-5f

// ---------------- preprocessing ----------------

__global__ void k_init(int* deg, int* cursor, int n) {
    int i = blockIdx.x * blockDim.x + threadIdx.x;
    if (i < n) { deg[i] = 1; cursor[i] = 0; }   // 1 = self-loop
}

__global__ void k_count(const int* __restrict__ dst, int* __restrict__ deg, int e) {
    int i = blockIdx.x * blockDim.x + threadIdx.x;
    if (i < e) atomicAdd(&deg[dst[i]], 1);
}

// inclusive scan of deg in 256-chunks
__global__ void k_scan_block(const int* __restrict__ deg, int* __restrict__ incl,
                             int* __restrict__ bsums, int n) {
    __shared__ int s[256];
    int i = blockIdx.x * 256 + threadIdx.x;
    int v = (i < n) ? deg[i] : 0;
    s[threadIdx.x] = v;
    __syncthreads();
    for (int off = 1; off < 256; off <<= 1) {
        int t = (threadIdx.x >= off) ? s[threadIdx.x - off] : 0;
        __syncthreads();
        s[threadIdx.x] += t;
        __syncthreads();
    }
    if (i < n) incl[i] = s[threadIdx.x];
    if (threadIdx.x == 255) bsums[blockIdx.x] = s[255];
}

// single-block exclusive scan of the block sums (nb <= 1024)
__global__ void k_scan_sums(int* bsums, int nb) {
    __shared__ int s[1024];
    int t = threadIdx.x;
    int orig = (t < nb) ? bsums[t] : 0;
    s[t] = orig;
    __syncthreads();
    for (int off = 1; off < 1024; off <<= 1) {
        int v = (t >= off) ? s[t - off] : 0;
        __syncthreads();
        s[t] += v;
        __syncthreads();
    }
    if (t < nb) bsums[t] = s[t] - orig;  // exclusive prefix
}

__global__ void k_finalize(const int* __restrict__ incl, const int* __restrict__ deg,
                           const int* __restrict__ bsums, int* __restrict__ row_ptr,
                           float* __restrict__ dis, int n, int total) {
    int i = blockIdx.x * blockDim.x + threadIdx.x;
    if (i < n) {
        row_ptr[i] = incl[i] - deg[i] + bsums[i >> 8];   // exclusive scan
        dis[i] = rsqrtf((float)deg[i]);                  // deg >= 1 always
    }
    if (i == 0) row_ptr[n] = total;
}

__global__ void k_fill(const int* __restrict__ src, const int* __restrict__ dst,
                       const int* __restrict__ row_ptr, int* __restrict__ cursor,
                       int* __restrict__ col, int e, int n) {
    int i = blockIdx.x * blockDim.x + threadIdx.x;
    int tot = e + n;
    if (i >= tot) return;
    int s_, d_;
    if (i < e) { s_ = src[i]; d_ = dst[i]; }
    else       { s_ = d_ = i - e; }          // self-loop
    int p = atomicAdd(&cursor[d_], 1);
    col[row_ptr[d_] + p] = s_;
}

// ---------------- per-round kernels ----------------

// h = x @ W.  lane = output column c; each lane holds W[:,c] in registers.
// x-row elements are wave-uniform broadcasts (L1-served float4).
__global__ __launch_bounds__(256) void k_gemm(const float* __restrict__ x,
                                              const float* __restrict__ W,
                                              float* __restrict__ h, int n) {
    const int lane = threadIdx.x & 63;
    const int wid  = threadIdx.x >> 6;   // wave id in block: 0..3
    float wc[D];
#pragma unroll
    for (int k = 0; k < D; ++k) wc[k] = W[k * D + lane];   // coalesced across lanes

    const int ROWS = 256;                // rows per block
    int r0 = blockIdx.x * ROWS;
    for (int rr = wid; rr < ROWS; rr += 4) {
        int r = r0 + rr;                 // wave-uniform
        if (r >= n) break;
        const float4* xr = (const float4*)(x + (size_t)r * D);
        float a0 = 0.f, a1 = 0.f, a2 = 0.f, a3 = 0.f;
#pragma unroll
        for (int kk = 0; kk < D / 4; ++kk) {
            float4 xv = xr[kk];
            a0 += xv.x * wc[4 * kk + 0];
            a1 += xv.y * wc[4 * kk + 1];
            a2 += xv.z * wc[4 * kk + 2];
            a3 += xv.w * wc[4 * kk + 3];
        }
        h[(size_t)r * D + lane] = (a0 + a1) + (a2 + a3);
    }
}

// fused CSR gather-aggregate + bias + LayerNorm. One wave per node, lane = feature.
__global__ __launch_bounds__(256) void k_agg_ln(
    const float* __restrict__ h, const int* __restrict__ row_ptr,
    const int* __restrict__ col, const float* __restrict__ dis,
    const float* __restrict__ b, const float* __restrict__ gamma,
    const float* __restrict__ beta, float* __restrict__ out, int n) {
    int w = (int)((blockIdx.x * (size_t)blockDim.x + threadIdx.x) >> 6);
    int lane = threadIdx.x & 63;
    if (w >= n) return;
    int jb = row_ptr[w], je = row_ptr[w + 1];
    float dv = dis[w];
    float acc = b[lane];
    for (int j = jb; j < je; ++j) {
        int u = col[j];                        // wave-uniform broadcast
        float wgt = dis[u] * dv;               // wave-uniform
        acc += wgt * h[(size_t)u * D + lane];  // coalesced 256B row read
    }
    // LayerNorm over the 64 lanes
    float s = acc;
#pragma unroll
    for (int m = 1; m < 64; m <<= 1) s += __shfl_xor(s, m, 64);
    float mu = s * (1.0f / 64.0f);
    float dif = acc - mu;
    float q = dif * dif;
#pragma unroll
    for (int m = 1; m < 64; m <<= 1) q += __shfl_xor(q, m, 64);
    float rstd = rsqrtf(q * (1.0f / 64.0f) + EPSV);
    out[(size_t)w * D + lane] = dif * rstd * gamma[lane] + beta[lane];
}

// ---------------- launch ----------------

extern "C" void kernel_launch(void* const* d_in, const int* in_sizes, int n_in,
                              void* d_out, int out_size, void* d_ws, size_t ws_size,
                              hipStream_t stream) {
    const float* x0    = (const float*)d_in[0];
    const int*   ei    = (const int*)d_in[1];
    const float* W     = (const float*)d_in[2];
    const float* b     = (const float*)d_in[3];
    const float* gamma = (const float*)d_in[4];
    const float* beta  = (const float*)d_in[5];
    // num_rounds (d_in[6]) is a device scalar; reference fixes it to 4.

    const int N = in_sizes[0] / D;
    const int E = in_sizes[1] / 2;
    const int* src = ei;
    const int* dst = ei + E;

    char* ws = (char*)d_ws;
    size_t off = 0;
    auto alloc = [&](size_t bytes) {
        off = (off + 255) & ~(size_t)255;
        void* p = ws + off;
        off += bytes;
        return p;
    };
    int*   deg     = (int*)alloc((size_t)N * 4);
    int*   cursor  = (int*)alloc((size_t)N * 4);
    int*   incl    = (int*)alloc((size_t)N * 4);
    int*   bsums   = (int*)alloc(4096);
    int*   row_ptr = (int*)alloc((size_t)(N + 1) * 4);
    float* dis     = (float*)alloc((size_t)N * 4);
    int*   col     = (int*)alloc((size_t)(E + N) * 4);
    float* h       = (float*)alloc((size_t)N * D * 4);
    (void)ws_size;

    const int nbN  = (N + 255) / 256;          // 391 — fits single-block sums scan
    const int nbE  = (E + 255) / 256;
    const int nbEN = (E + N + 255) / 256;

    k_init<<<nbN, 256, 0, stream>>>(deg, cursor, N);
    k_count<<<nbE, 256, 0, stream>>>(dst, deg, E);
    k_scan_block<<<nbN, 256, 0, stream>>>(deg, incl, bsums, N);
    k_scan_sums<<<1, 1024, 0, stream>>>(bsums, nbN);
    k_finalize<<<nbN, 256, 0, stream>>>(incl, deg, bsums, row_ptr, dis, N, E + N);
    k_fill<<<nbEN, 256, 0, stream>>>(src, dst, row_ptr, cursor, col, E, N);

    float* out = (float*)d_out;
    const float* xin = x0;
    const int nbAgg = (int)(((size_t)N * 64 + 255) / 256);
    for (int r = 0; r < 4; ++r) {
        k_gemm<<<nbN, 256, 0, stream>>>(xin, W, h, N);
        k_agg_ln<<<nbAgg, 256, 0, stream>>>(h, row_ptr, col, dis, b, gamma, beta, out, N);
        xin = out;
    }
}

// Round 2
// 783.425 us; speedup vs baseline: 1.2092x; 1.2092x over previous
//
#include <hip/hip_runtime.h>

#define D 64
#define EPSV 1e-5f

// ---------------- preprocessing ----------------

__global__ void k_init(int* deg, int* cursor, int n) {
    int i = blockIdx.x * blockDim.x + threadIdx.x;
    if (i < n) { deg[i] = 1; cursor[i] = 0; }   // 1 = self-loop
}

__global__ void k_count(const int* __restrict__ dst, int* __restrict__ deg, int e) {
    int i = blockIdx.x * blockDim.x + threadIdx.x;
    if (i < e) atomicAdd(&deg[dst[i]], 1);
}

// inclusive scan of deg in 256-chunks
__global__ void k_scan_block(const int* __restrict__ deg, int* __restrict__ incl,
                             int* __restrict__ bsums, int n) {
    __shared__ int s[256];
    int i = blockIdx.x * 256 + threadIdx.x;
    int v = (i < n) ? deg[i] : 0;
    s[threadIdx.x] = v;
    __syncthreads();
    for (int off = 1; off < 256; off <<= 1) {
        int t = (threadIdx.x >= off) ? s[threadIdx.x - off] : 0;
        __syncthreads();
        s[threadIdx.x] += t;
        __syncthreads();
    }
    if (i < n) incl[i] = s[threadIdx.x];
    if (threadIdx.x == 255) bsums[blockIdx.x] = s[255];
}

// single-block exclusive scan of the block sums (nb <= 1024)
__global__ void k_scan_sums(int* bsums, int nb) {
    __shared__ int s[1024];
    int t = threadIdx.x;
    int orig = (t < nb) ? bsums[t] : 0;
    s[t] = orig;
    __syncthreads();
    for (int off = 1; off < 1024; off <<= 1) {
        int v = (t >= off) ? s[t - off] : 0;
        __syncthreads();
        s[t] += v;
        __syncthreads();
    }
    if (t < nb) bsums[t] = s[t] - orig;  // exclusive prefix
}

__global__ void k_finalize(const int* __restrict__ incl, const int* __restrict__ deg,
                           const int* __restrict__ bsums, int* __restrict__ row_ptr,
                           float* __restrict__ dis, int n, int total) {
    int i = blockIdx.x * blockDim.x + threadIdx.x;
    if (i < n) {
        row_ptr[i] = incl[i] - deg[i] + bsums[i >> 8];   // exclusive scan
        dis[i] = rsqrtf((float)deg[i]);                  // deg >= 1 always
    }
    if (i == 0) row_ptr[n] = total;
}

__global__ void k_fill(const int* __restrict__ src, const int* __restrict__ dst,
                       const int* __restrict__ row_ptr, int* __restrict__ cursor,
                       int* __restrict__ col, int e, int n) {
    int i = blockIdx.x * blockDim.x + threadIdx.x;
    int tot = e + n;
    if (i >= tot) return;
    int s_, d_;
    if (i < e) { s_ = src[i]; d_ = dst[i]; }
    else       { s_ = d_ = i - e; }          // self-loop
    int p = atomicAdd(&cursor[d_], 1);
    col[row_ptr[d_] + p] = s_;
}

// Wt[c][k] = W[k][c] so lane c can load its W-column contiguously (16 float4s)
__global__ void k_transpose(const float* __restrict__ W, float* __restrict__ Wt) {
    for (int i = threadIdx.x; i < D * D; i += blockDim.x) {
        int k = i >> 6, c = i & 63;
        Wt[c * D + k] = W[k * D + c];
    }
}

// ---------------- fused per-round kernel ----------------
// One wave per node (grid-strided). Exploits GCN linearity:
//   agg = (sum_u norm_u * x[u]) @ W + b   — no materialized h.
// lane = feature index. Gather -> in-register transform -> in-register LN.
__global__ __launch_bounds__(256) void k_round(
    const float* __restrict__ x, const int* __restrict__ row_ptr,
    const int* __restrict__ col, const float* __restrict__ dis,
    const float* __restrict__ Wt, const float* __restrict__ b,
    const float* __restrict__ gamma, const float* __restrict__ beta,
    float* __restrict__ out, int n, int nwaves) {
    const int lane = threadIdx.x & 63;
    const int wgl  = blockIdx.x * 4 + (threadIdx.x >> 6);

    // W column for this lane: wt[k] holds W[4k..4k+3][lane]
    float4 wt[16];
    const float4* wrow = (const float4*)(Wt + (size_t)lane * D);
#pragma unroll
    for (int k = 0; k < 16; ++k) wt[k] = wrow[k];

    const float bl = b[lane], gl = gamma[lane], be = beta[lane];

    for (int w = wgl; w < n; w += nwaves) {
        const int jb = row_ptr[w], je = row_ptr[w + 1];
        float acc = 0.f;
        for (int jc = jb; jc < je; jc += 64) {
            int m = je - jc; if (m > 64) m = 64;
            int u = 0; float nm = 0.f;
            if (lane < m) { u = col[jc + lane]; nm = dis[u]; }
            int j = 0;
            for (; j + 4 <= m; j += 4) {
                int u0 = __shfl(u, j),     u1 = __shfl(u, j + 1);
                int u2 = __shfl(u, j + 2), u3 = __shfl(u, j + 3);
                float n0 = __shfl(nm, j),     n1 = __shfl(nm, j + 1);
                float n2 = __shfl(nm, j + 2), n3 = __shfl(nm, j + 3);
                float x0v = x[(size_t)u0 * D + lane];
                float x1v = x[(size_t)u1 * D + lane];
                float x2v = x[(size_t)u2 * D + lane];
                float x3v = x[(size_t)u3 * D + lane];
                acc += n0 * x0v; acc += n1 * x1v;
                acc += n2 * x2v; acc += n3 * x3v;
            }
            for (; j < m; ++j) {
                int uu = __shfl(u, j); float nn = __shfl(nm, j);
                acc += nn * x[(size_t)uu * D + lane];
            }
        }
        acc *= dis[w];   // norm = dis[u]*dis[w]; dis[w] factored out of the sum

        // y[lane] = sum_k acc[k] * W[k][lane] + b[lane]
        float y = bl;
#pragma unroll
        for (int k = 0; k < 16; ++k) {
            float a0 = __shfl(acc, 4 * k),     a1 = __shfl(acc, 4 * k + 1);
            float a2 = __shfl(acc, 4 * k + 2), a3 = __shfl(acc, 4 * k + 3);
            y += a0 * wt[k].x; y += a1 * wt[k].y;
            y += a2 * wt[k].z; y += a3 * wt[k].w;
        }

        // LayerNorm across the 64 lanes
        float s = y;
#pragma unroll
        for (int msk = 1; msk < 64; msk <<= 1) s += __shfl_xor(s, msk, 64);
        float mu = s * (1.0f / 64.0f);
        float dif = y - mu;
        float q = dif * dif;
#pragma unroll
        for (int msk = 1; msk < 64; msk <<= 1) q += __shfl_xor(q, msk, 64);
        float rstd = rsqrtf(q * (1.0f / 64.0f) + EPSV);
        out[(size_t)w * D + lane] = dif * rstd * gl + be;
    }
}

// ---------------- launch ----------------

extern "C" void kernel_launch(void* const* d_in, const int* in_sizes, int n_in,
                              void* d_out, int out_size, void* d_ws, size_t ws_size,
                              hipStream_t stream) {
    const float* x0    = (const float*)d_in[0];
    const int*   ei    = (const int*)d_in[1];
    const float* W     = (const float*)d_in[2];
    const float* b     = (const float*)d_in[3];
    const float* gamma = (const float*)d_in[4];
    const float* beta  = (const float*)d_in[5];

    const int N = in_sizes[0] / D;
    const int E = in_sizes[1] / 2;
    const int* src = ei;
    const int* dst = ei + E;

    char* ws = (char*)d_ws;
    size_t off = 0;
    auto alloc = [&](size_t bytes) {
        off = (off + 255) & ~(size_t)255;
        void* p = ws + off;
        off += bytes;
        return p;
    };
    int*   deg     = (int*)alloc((size_t)N * 4);
    int*   cursor  = (int*)alloc((size_t)N * 4);
    int*   incl    = (int*)alloc((size_t)N * 4);
    int*   bsums   = (int*)alloc(4096);
    int*   row_ptr = (int*)alloc((size_t)(N + 1) * 4);
    float* dis     = (float*)alloc((size_t)N * 4);
    int*   col     = (int*)alloc((size_t)(E + N) * 4);
    float* Wt      = (float*)alloc((size_t)D * D * 4);
    float* t       = (float*)alloc((size_t)N * D * 4);
    (void)ws_size;

    const int nbN  = (N + 255) / 256;
    const int nbE  = (E + 255) / 256;
    const int nbEN = (E + N + 255) / 256;

    k_init<<<nbN, 256, 0, stream>>>(deg, cursor, N);
    k_count<<<nbE, 256, 0, stream>>>(dst, deg, E);
    k_scan_block<<<nbN, 256, 0, stream>>>(deg, incl, bsums, N);
    k_scan_sums<<<1, 1024, 0, stream>>>(bsums, nbN);
    k_finalize<<<nbN, 256, 0, stream>>>(incl, deg, bsums, row_ptr, dis, N, E + N);
    k_fill<<<nbEN, 256, 0, stream>>>(src, dst, row_ptr, cursor, col, E, N);
    k_transpose<<<1, 256, 0, stream>>>(W, Wt);

    float* out = (float*)d_out;
    const int GRID = 1280;                 // 5120 waves, ~20 nodes/wave
    const int NW   = GRID * 4;
    // ping-pong: x0 -> t -> out -> t -> out
    k_round<<<GRID, 256, 0, stream>>>(x0,  row_ptr, col, dis, Wt, b, gamma, beta, t,   N, NW);
    k_round<<<GRID, 256, 0, stream>>>(t,   row_ptr, col, dis, Wt, b, gamma, beta, out, N, NW);
    k_round<<<GRID, 256, 0, stream>>>(out, row_ptr, col, dis, Wt, b, gamma, beta, t,   N, NW);
    k_round<<<GRID, 256, 0, stream>>>(t,   row_ptr, col, dis, Wt, b, gamma, beta, out, N, NW);
}